// Round 5
// baseline (270.069 us; speedup 1.0000x reference)
//
#include <hip/hip_runtime.h>

#define B_ 2048
#define L_ 200
#define D_ 128
#define NITEMS 50000
#define NTILES ((B_ * L_) / 16)   // 25600

typedef __attribute__((ext_vector_type(8))) short short8v;
typedef __attribute__((ext_vector_type(4))) float floatx4;

// ---------------- helpers ----------------
__device__ __forceinline__ short f2bf(float f) {
    union { float f; unsigned u; } v;
    v.f = f;
    unsigned r = v.u + 0x7FFFu + ((v.u >> 16) & 1u);
    return (short)(r >> 16);
}
__device__ __forceinline__ float bf2f(short s) {
    union { unsigned u; float f; } v;
    v.u = ((unsigned)(unsigned short)s) << 16;
    return v.f;
}

__device__ __forceinline__ float fast_tanh(float x) {
    x = fminf(fmaxf(x, -15.f), 15.f);
    const float t = exp2f(x * 2.885390081777927f);  // e^(2x)
    return (t - 1.f) * __builtin_amdgcn_rcpf(t + 1.f);
}

__device__ __forceinline__ float wave_sum(float v) {
#pragma unroll
    for (int m = 32; m >= 1; m >>= 1) v += __shfl_xor(v, m, 64);
    return v;
}
__device__ __forceinline__ float wave_max(float v) {
#pragma unroll
    for (int m = 32; m >= 1; m >>= 1) v = fmaxf(v, __shfl_xor(v, m, 64));
    return v;
}

// ---------------- K0: item_embed -> bf16 table ----------------
__global__ __launch_bounds__(256) void k0_cvt(const float* __restrict__ src,
                                              short* __restrict__ dst, int n8) {
    const int i = blockIdx.x * 256 + threadIdx.x;
    if (i >= n8) return;
    const float4 f0 = *reinterpret_cast<const float4*>(src + i * 8);
    const float4 f1 = *reinterpret_cast<const float4*>(src + i * 8 + 4);
    short8v w;
    w[0] = f2bf(f0.x); w[1] = f2bf(f0.y); w[2] = f2bf(f0.z); w[3] = f2bf(f0.w);
    w[4] = f2bf(f1.x); w[5] = f2bf(f1.y); w[6] = f2bf(f1.z); w[7] = f2bf(f1.w);
    *reinterpret_cast<short8v*>(dst + i * 8) = w;
}

// ---------------- K1: Mbf = bf16( Wk @ W_h ) ----------------
__global__ __launch_bounds__(128) void k1_M(const float* __restrict__ Wk,
                                            const float* __restrict__ Wh,
                                            short* __restrict__ Mbf) {
    __shared__ float wk[128];
    const int e = blockIdx.x, c = threadIdx.x;
    wk[c] = Wk[e * 128 + c];
    __syncthreads();
    float s = 0.f;
#pragma unroll 4
    for (int d = 0; d < 128; ++d) s += wk[d] * Wh[d * 128 + c];
    Mbf[e * 128 + c] = f2bf(s);
}

// ---------------- K2: per-b prep ----------------
__global__ __launch_bounds__(128) void k2_prep(
    const int* __restrict__ user_idx, const int* __restrict__ item_idx,
    const int* __restrict__ user_hist, const float* __restrict__ user_embed,
    const float* __restrict__ item_embed, const float* __restrict__ W_i,
    const float* __restrict__ Wq, float* __restrict__ uid_o,
    float* __restrict__ tid_o, float* __restrict__ qu_o, float* __restrict__ qt_o,
    int* __restrict__ hist_o, float* __restrict__ maskf_o) {
    const int b = blockIdx.x, t = threadIdx.x;
    const int ui = user_idx[b], ii = item_idx[b];
    __shared__ float uid_s[128], traw_s[128], tid_s[128];
    const float uv = user_embed[(long)ui * 128 + t];
    const float tv = item_embed[(long)ii * 128 + t];
    uid_s[t] = uv;
    traw_s[t] = tv;
    uid_o[b * 128 + t] = uv;
    for (int l = t; l < L_; l += 128) {
        const int hv = user_hist[(long)ui * L_ + l];
        hist_o[b * L_ + l] = hv;
        maskf_o[b * L_ + l] = (hv != ii && hv != NITEMS) ? 1.f : 0.f;
    }
    __syncthreads();
    float tidv = 0.f, quv = 0.f;
#pragma unroll 2
    for (int c = 0; c < 128; c += 4) {
        const float4 wi = *reinterpret_cast<const float4*>(&W_i[t * 128 + c]);
        const float4 wq = *reinterpret_cast<const float4*>(&Wq[t * 128 + c]);
        tidv += wi.x * traw_s[c] + wi.y * traw_s[c + 1] + wi.z * traw_s[c + 2] + wi.w * traw_s[c + 3];
        quv  += wq.x * uid_s[c]  + wq.y * uid_s[c + 1]  + wq.z * uid_s[c + 2]  + wq.w * uid_s[c + 3];
    }
    tid_s[t] = tidv;
    tid_o[b * 128 + t] = tidv;
    qu_o[b * 128 + t] = quv;
    __syncthreads();
    float qtv = 0.f;
#pragma unroll 2
    for (int c = 0; c < 128; c += 4) {
        const float4 wq = *reinterpret_cast<const float4*>(&Wq[t * 128 + c]);
        qtv += wq.x * tid_s[c] + wq.y * tid_s[c + 1] + wq.z * tid_s[c + 2] + wq.w * tid_s[c + 3];
    }
    qt_o[b * 128 + t] = qtv;
}

// ---------------- K3: wave-independent MFMA score tiles ----------------
// Transposed: A-operand = M rows (m = e), B-operand = gathered rows (n = r).
// One barrier total (M staging); tiles processed grid-stride per wave with
// B-fragments loaded straight from global (4x16B/lane) — no per-tile sync.
__global__ __launch_bounds__(256, 4) void k3_scores(
    const short* __restrict__ Mbf, const short* __restrict__ item_bf,
    const int* __restrict__ hist_g, const float* __restrict__ qu_,
    const float* __restrict__ qt_, const float* __restrict__ v_attn,
    float* __restrict__ scu, float* __restrict__ sci) {
    __shared__ __align__(16) short M_lds[8][4][4][16][8];  // [t8][ks][g][lo][8] = 32KB
    const int t = threadIdx.x;

    // stage M once, fragment order, coalesced global reads
#pragma unroll
    for (int c8 = 0; c8 < 8; ++c8) {
        const int flat = c8 * 256 + t;
        const int g = flat & 3, ks = (flat >> 2) & 3;
        const int lo = (flat >> 4) & 15, t8 = flat >> 8;
        *reinterpret_cast<short8v*>(&M_lds[t8][ks][g][lo][0]) =
            *reinterpret_cast<const short8v*>(Mbf + (t8 * 16 + lo) * 128 + ks * 32 + g * 8);
    }
    __syncthreads();

    const int l = t & 63;
    const int lo = l & 15, hi = l >> 4;
    const int nwaves = gridDim.x * 4;
    const int wg = blockIdx.x * 4 + (t >> 6);

    for (int tile = wg; tile < NTILES; tile += nwaves) {
        const int r = tile * 16 + lo;
        const int b = r / L_;
        const int idx = hist_g[r];
        const short* rowp = item_bf + (long)idx * 128;

        short8v bfrag[4];
#pragma unroll
        for (int ks = 0; ks < 4; ++ks)
            bfrag[ks] = *reinterpret_cast<const short8v*>(rowp + ks * 32 + hi * 8);

        floatx4 acc[8];
#pragma unroll
        for (int t8 = 0; t8 < 8; ++t8) acc[t8] = (floatx4){0.f, 0.f, 0.f, 0.f};
#pragma unroll
        for (int ks = 0; ks < 4; ++ks)
#pragma unroll
            for (int t8 = 0; t8 < 8; ++t8)
                acc[t8] = __builtin_amdgcn_mfma_f32_16x16x32_bf16(
                    *reinterpret_cast<const short8v*>(&M_lds[t8][ks][hi][lo][0]),
                    bfrag[ks], acc[t8], 0, 0, 0);

        // epilogue: lane owns output row r; e = t8*16 + hi*4 + reg
        float su = 0.f, si = 0.f;
#pragma unroll
        for (int t8 = 0; t8 < 8; ++t8) {
            const floatx4 vv  = *reinterpret_cast<const floatx4*>(v_attn + t8 * 16 + hi * 4);
            const floatx4 qu4 = *reinterpret_cast<const floatx4*>(qu_ + b * 128 + t8 * 16 + hi * 4);
            const floatx4 qt4 = *reinterpret_cast<const floatx4*>(qt_ + b * 128 + t8 * 16 + hi * 4);
#pragma unroll
            for (int reg = 0; reg < 4; ++reg) {
                const float kw = acc[t8][reg];
                su += vv[reg] * fast_tanh(qu4[reg] + kw);
                si += vv[reg] * fast_tanh(qt4[reg] + kw);
            }
        }
        su += __shfl_xor(su, 16, 64);
        su += __shfl_xor(su, 32, 64);
        si += __shfl_xor(si, 16, 64);
        si += __shfl_xor(si, 32, 64);
        if (hi == 0) {
            scu[r] = su * 0.25f;  // /TAU
            sci[r] = si * 0.25f;
        }
    }
}

// ---------------- K45: softmax + KL + attn apply + W_h + LN + logit ----------------
// Block per b. Phase A: each wave redundantly computes the softmax/weights
// (barrier-free wave reductions); attn kept in LDS. Phase B: gather-apply with
// l-range split in halves. Phase C: W_h matvec (u rows on half 0, i rows on
// half 1), LayerNorms, logit.
__global__ __launch_bounds__(256) void k45_fused(
    const float* __restrict__ scu, const float* __restrict__ sci,
    const float* __restrict__ maskf, const float* __restrict__ noise_u,
    const float* __restrict__ noise_i, const int* __restrict__ hist_g,
    const short* __restrict__ item_bf, const float* __restrict__ W_h,
    const float* __restrict__ uid, const float* __restrict__ tid,
    const float* __restrict__ gamma_u, const float* __restrict__ beta_u,
    const float* __restrict__ gamma_i, const float* __restrict__ beta_i,
    const float* __restrict__ pred_W, const float* __restrict__ pred_b,
    float* __restrict__ klu, float* __restrict__ kli, float* __restrict__ msm,
    float* __restrict__ out) {
    const int b = blockIdx.x, t = threadIdx.x;
    const int wid = t >> 6, lane = t & 63;
    const int base = b * L_;

    __shared__ float au[L_], ai[L_];
    __shared__ int hg[L_];
    __shared__ float aru[128], ari[128];
    __shared__ float parts[2][2][128];
    __shared__ float ui_s[2][128];
    __shared__ float red[8];

    for (int l0 = t; l0 < L_; l0 += 256) hg[l0] = hist_g[base + l0];

    // ---- Phase A (redundant per wave, no barriers) ----
    {
        const float* sc_[2] = {scu, sci};
        const float* nz_[2] = {noise_u, noise_i};
        float attv[2][4], kls_[2];
        float mk[4];
        float msl = 0.f;
#pragma unroll
        for (int k = 0; k < 4; ++k) {
            const int l = lane + 64 * k;
            mk[k] = (l < L_) ? maskf[base + l] : 0.f;
            msl += mk[k];
        }
        const float msum = wave_sum(msl);
#pragma unroll
        for (int side = 0; side < 2; ++side) {
            float s[4];
            float mloc = -1e30f;
#pragma unroll
            for (int k = 0; k < 4; ++k) {
                const int l = lane + 64 * k;
                s[k] = (l < L_) ? (mk[k] > 0.5f ? sc_[side][base + l] : -1e9f) : -1e30f;
                mloc = fmaxf(mloc, s[k]);
            }
            const float mx = wave_max(mloc);
            float e[4], esum = 0.f;
#pragma unroll
            for (int k = 0; k < 4; ++k) {
                const int l = lane + 64 * k;
                e[k] = (l < L_) ? expf(s[k] - mx) : 0.f;
                esum += e[k];
            }
            const float Z = wave_sum(esum);
            const float invZ = 1.f / Z;
            float wt[4], wsum = 0.f, klsum = 0.f;
#pragma unroll
            for (int k = 0; k < 4; ++k) {
                const int l = lane + 64 * k;
                const float phi = e[k] * invZ;
                const float mu = logf(phi + 1e-8f);
                wt[k] = (l < L_) ? expf(mu + 0.1f * nz_[side][base + l]) * mk[k] : 0.f;
                wsum += wt[k];
                klsum += (l < L_) ? (2.3025850929940457f + 0.5f * (0.01f + mu * mu) - 0.5f) * mk[k] : 0.f;
            }
            const float Zw = wave_sum(wsum);
            const float invZw = 1.f / (Zw + 1e-8f);
#pragma unroll
            for (int k = 0; k < 4; ++k) attv[side][k] = wt[k] * invZw;
            kls_[side] = wave_sum(klsum);
        }
        if (wid == 0) {
#pragma unroll
            for (int k = 0; k < 4; ++k) {
                const int l = lane + 64 * k;
                if (l < L_) au[l] = attv[0][k];
            }
        } else if (wid == 1) {
#pragma unroll
            for (int k = 0; k < 4; ++k) {
                const int l = lane + 64 * k;
                if (l < L_) ai[l] = attv[1][k];
            }
        } else if (wid == 2 && lane == 0) {
            klu[b] = kls_[0];
            kli[b] = kls_[1];
            msm[b] = msum;
        }
    }
    __syncthreads();

    // ---- Phase B: attn-weighted gather-sum, l-range split in halves ----
    const int half = t >> 7, tl = t & 127;
    {
        float su = 0.f, si = 0.f;
        const int l0 = half * 100;
#pragma unroll 4
        for (int l = l0; l < l0 + 100; ++l) {
            const float h = bf2f(item_bf[(long)hg[l] * 128 + tl]);
            su += au[l] * h;
            si += ai[l] * h;
        }
        parts[0][half][tl] = su;
        parts[1][half][tl] = si;
    }
    __syncthreads();
    if (half == 0) aru[tl] = parts[0][0][tl] + parts[0][1][tl];
    else           ari[tl] = parts[1][0][tl] + parts[1][1][tl];
    __syncthreads();

    // ---- Phase C: W_h matvec (half 0 = u, half 1 = i), LN, logit ----
    const float* vsrc = half ? ari : aru;
    float o = 0.f;
#pragma unroll 2
    for (int c = 0; c < 128; c += 4) {
        const float4 w = *reinterpret_cast<const float4*>(&W_h[tl * 128 + c]);
        o += w.x * vsrc[c] + w.y * vsrc[c + 1] + w.z * vsrc[c + 2] + w.w * vsrc[c + 3];
    }
    const float x = o * (half ? tid[b * 128 + tl] : uid[b * 128 + tl]);

    float v1 = wave_sum(x);
    if (lane == 0) red[wid] = v1;
    __syncthreads();
    const float mean = (red[half * 2] + red[half * 2 + 1]) * (1.f / 128.f);
    const float d = x - mean;
    float v2 = wave_sum(d * d);
    __syncthreads();
    if (lane == 0) red[wid] = v2;
    __syncthreads();
    const float var = (red[half * 2] + red[half * 2 + 1]) * (1.f / 128.f);
    const float gmm = half ? gamma_i[tl] : gamma_u[tl];
    const float bta = half ? beta_i[tl] : beta_u[tl];
    ui_s[half][tl] = d * rsqrtf(var + 1e-5f) * gmm + bta;
    __syncthreads();
    if (half == 0) {
        const float p = ui_s[0][tl] * ui_s[1][tl] * pred_W[tl];
        const float v3 = wave_sum(p);
        if (lane == 0) red[4 + wid] = v3;
    }
    __syncthreads();
    if (t == 0) out[b] = red[4] + red[5] + pred_b[0];
}

// ---------------- K6: KL final reduction ----------------
__global__ __launch_bounds__(256) void k6_kl(const float* __restrict__ klu,
                                             const float* __restrict__ kli,
                                             const float* __restrict__ msm,
                                             float* __restrict__ out) {
    __shared__ float red[4];
    const int t = threadIdx.x;
    float su = 0.f, si = 0.f, sm = 0.f;
    for (int b = t; b < B_; b += 256) {
        su += klu[b];
        si += kli[b];
        sm += msm[b];
    }
    su = wave_sum(su);
    si = wave_sum(si);
    sm = wave_sum(sm);
    __syncthreads();
    if ((t & 63) == 0) red[t >> 6] = su;
    __syncthreads();
    su = red[0] + red[1] + red[2] + red[3];
    __syncthreads();
    if ((t & 63) == 0) red[t >> 6] = si;
    __syncthreads();
    si = red[0] + red[1] + red[2] + red[3];
    __syncthreads();
    if ((t & 63) == 0) red[t >> 6] = sm;
    __syncthreads();
    sm = red[0] + red[1] + red[2] + red[3];
    if (t == 0) {
        const float inv = 1.f / (sm + 1e-8f);
        out[0] = 0.5f * (su * inv + si * inv);
    }
}

extern "C" void kernel_launch(void* const* d_in, const int* in_sizes, int n_in,
                              void* d_out, int out_size, void* d_ws, size_t ws_size,
                              hipStream_t stream) {
    const int* user_idx = (const int*)d_in[0];
    const int* item_idx = (const int*)d_in[1];
    const int* user_hist = (const int*)d_in[2];
    const float* user_embed = (const float*)d_in[3];
    const float* item_embed = (const float*)d_in[4];
    const float* W_i = (const float*)d_in[5];
    const float* W_h = (const float*)d_in[6];
    const float* Wq = (const float*)d_in[7];
    const float* Wk = (const float*)d_in[8];
    const float* v_attn = (const float*)d_in[9];
    const float* pred_W = (const float*)d_in[10];
    const float* pred_b = (const float*)d_in[11];
    const float* gamma_u = (const float*)d_in[12];
    const float* beta_u = (const float*)d_in[13];
    const float* gamma_i = (const float*)d_in[14];
    const float* beta_i = (const float*)d_in[15];
    const float* noise_u = (const float*)d_in[16];
    const float* noise_i = (const float*)d_in[17];
    float* out = (float*)d_out;

    char* ws = (char*)d_ws;
    size_t off = 0;
    auto alloc = [&](size_t bytes) -> void* {
        void* p = ws + off;
        off = (off + bytes + 255) & ~(size_t)255;
        return p;
    };
    short* Mbf     = (short*)alloc(128 * 128 * 2);
    short* item_bf = (short*)alloc((size_t)(NITEMS + 1) * 128 * 2);
    float* uid = (float*)alloc((size_t)B_ * 128 * 4);
    float* tid = (float*)alloc((size_t)B_ * 128 * 4);
    float* qu  = (float*)alloc((size_t)B_ * 128 * 4);
    float* qt  = (float*)alloc((size_t)B_ * 128 * 4);
    int* hg    = (int*)alloc((size_t)B_ * L_ * 4);
    float* mkf = (float*)alloc((size_t)B_ * L_ * 4);
    float* scu = (float*)alloc((size_t)B_ * L_ * 4);
    float* sci = (float*)alloc((size_t)B_ * L_ * 4);
    float* klu = (float*)alloc((size_t)B_ * 4);
    float* kli = (float*)alloc((size_t)B_ * 4);
    float* msm = (float*)alloc((size_t)B_ * 4);

    const int n8 = (NITEMS + 1) * 128 / 8;
    k0_cvt<<<(n8 + 255) / 256, 256, 0, stream>>>(item_embed, item_bf, n8);
    k1_M<<<128, 128, 0, stream>>>(Wk, W_h, Mbf);
    k2_prep<<<B_, 128, 0, stream>>>(user_idx, item_idx, user_hist, user_embed,
                                    item_embed, W_i, Wq, uid, tid, qu, qt, hg, mkf);
    k3_scores<<<1280, 256, 0, stream>>>(Mbf, item_bf, hg, qu, qt, v_attn, scu, sci);
    k45_fused<<<B_, 256, 0, stream>>>(scu, sci, mkf, noise_u, noise_i, hg, item_bf,
                                      W_h, uid, tid, gamma_u, beta_u, gamma_i, beta_i,
                                      pred_W, pred_b, klu, kli, msm, out);
    k6_kl<<<1, 256, 0, stream>>>(klu, kli, msm, out + B_);
}

// Round 6
// 145.618 us; speedup vs baseline: 1.8546x; 1.8546x over previous
//
#include <hip/hip_runtime.h>

#define B_ 2048
#define L_ 200
#define D_ 128
#define NITEMS 50000
#define NROWS (B_ * L_)
#define GROUPS_TOTAL (NROWS / 64)   // 6400
#define K3_BLOCKS 512

typedef __attribute__((ext_vector_type(8))) short short8v;
typedef __attribute__((ext_vector_type(4))) float floatx4;

// ---------------- helpers ----------------
__device__ __forceinline__ short f2bf(float f) {
    union { float f; unsigned u; } v;
    v.f = f;
    unsigned r = v.u + 0x7FFFu + ((v.u >> 16) & 1u);
    return (short)(r >> 16);
}
__device__ __forceinline__ float bf2f(short s) {
    union { unsigned u; float f; } v;
    v.u = ((unsigned)(unsigned short)s) << 16;
    return v.f;
}

__device__ __forceinline__ float fast_tanh(float x) {
    x = fminf(fmaxf(x, -15.f), 15.f);
    const float t = exp2f(x * 2.885390081777927f);  // e^(2x)
    return (t - 1.f) * __builtin_amdgcn_rcpf(t + 1.f);
}
// Taylor to x^7, |x|<=0.5: err < 5e-5
__device__ __forceinline__ float tanh_poly(float x) {
    const float x2 = x * x;
    return x + x * x2 * (-0.33333333f + x2 * (0.13333333f + x2 * (-0.05396825f)));
}

__device__ __forceinline__ float wave_sum(float v) {
#pragma unroll
    for (int m = 32; m >= 1; m >>= 1) v += __shfl_xor(v, m, 64);
    return v;
}
__device__ __forceinline__ float wave_max(float v) {
#pragma unroll
    for (int m = 32; m >= 1; m >>= 1) v = fmaxf(v, __shfl_xor(v, m, 64));
    return v;
}

// ---------------- K0: item_embed -> bf16 table ----------------
__global__ __launch_bounds__(256) void k0_cvt(const float* __restrict__ src,
                                              short* __restrict__ dst, int n8) {
    const int i = blockIdx.x * 256 + threadIdx.x;
    if (i >= n8) return;
    const float4 f0 = *reinterpret_cast<const float4*>(src + i * 8);
    const float4 f1 = *reinterpret_cast<const float4*>(src + i * 8 + 4);
    short8v w;
    w[0] = f2bf(f0.x); w[1] = f2bf(f0.y); w[2] = f2bf(f0.z); w[3] = f2bf(f0.w);
    w[4] = f2bf(f1.x); w[5] = f2bf(f1.y); w[6] = f2bf(f1.z); w[7] = f2bf(f1.w);
    *reinterpret_cast<short8v*>(dst + i * 8) = w;
}

// ---------------- K1: Mbf = bf16( Wk @ W_h ) ----------------
__global__ __launch_bounds__(128) void k1_M(const float* __restrict__ Wk,
                                            const float* __restrict__ Wh,
                                            short* __restrict__ Mbf) {
    __shared__ float wk[128];
    const int e = blockIdx.x, c = threadIdx.x;
    wk[c] = Wk[e * 128 + c];
    __syncthreads();
    float s = 0.f;
#pragma unroll 4
    for (int d = 0; d < 128; ++d) s += wk[d] * Wh[d * 128 + c];
    Mbf[e * 128 + c] = f2bf(s);
}

// ---------------- K2: batched per-b prep (8 b per block) ----------------
__global__ __launch_bounds__(128) void k2_prep(
    const int* __restrict__ user_idx, const int* __restrict__ item_idx,
    const int* __restrict__ user_hist, const float* __restrict__ user_embed,
    const float* __restrict__ item_embed, const float* __restrict__ W_i,
    const float* __restrict__ Wq, float* __restrict__ uid_o,
    float* __restrict__ tid_o, float* __restrict__ qu_o, float* __restrict__ qt_o,
    int* __restrict__ hist_o, float* __restrict__ maskf_o) {
    const int bb = blockIdx.x * 8, t = threadIdx.x;
    __shared__ float uid_s[8][128], traw_s[8][128], tid_s[8][128];
    __shared__ int ui_s[8], ii_s[8];
    if (t < 8) {
        ui_s[t] = user_idx[bb + t];
        ii_s[t] = item_idx[bb + t];
    }
    __syncthreads();
#pragma unroll
    for (int k = 0; k < 8; ++k) {
        const float uv = user_embed[(long)ui_s[k] * 128 + t];
        const float tv = item_embed[(long)ii_s[k] * 128 + t];
        uid_s[k][t] = uv;
        traw_s[k][t] = tv;
        uid_o[(bb + k) * 128 + t] = uv;
        for (int l = t; l < L_; l += 128) {
            const int hv = user_hist[(long)ui_s[k] * L_ + l];
            hist_o[(bb + k) * L_ + l] = hv;
            maskf_o[(bb + k) * L_ + l] = (hv != ii_s[k] && hv != NITEMS) ? 1.f : 0.f;
        }
    }
    __syncthreads();
    {
        float at[8] = {0.f, 0.f, 0.f, 0.f, 0.f, 0.f, 0.f, 0.f};
        float aq[8] = {0.f, 0.f, 0.f, 0.f, 0.f, 0.f, 0.f, 0.f};
        for (int c = 0; c < 128; c += 4) {
            const float4 wi = *reinterpret_cast<const float4*>(&W_i[t * 128 + c]);
            const float4 wq = *reinterpret_cast<const float4*>(&Wq[t * 128 + c]);
#pragma unroll
            for (int k = 0; k < 8; ++k) {
                const float4 tr = *reinterpret_cast<const float4*>(&traw_s[k][c]);
                const float4 ud = *reinterpret_cast<const float4*>(&uid_s[k][c]);
                at[k] += wi.x * tr.x + wi.y * tr.y + wi.z * tr.z + wi.w * tr.w;
                aq[k] += wq.x * ud.x + wq.y * ud.y + wq.z * ud.z + wq.w * ud.w;
            }
        }
#pragma unroll
        for (int k = 0; k < 8; ++k) {
            tid_s[k][t] = at[k];
            tid_o[(bb + k) * 128 + t] = at[k];
            qu_o[(bb + k) * 128 + t] = aq[k];
        }
    }
    __syncthreads();
    {
        float aqt[8] = {0.f, 0.f, 0.f, 0.f, 0.f, 0.f, 0.f, 0.f};
        for (int c = 0; c < 128; c += 4) {
            const float4 wq = *reinterpret_cast<const float4*>(&Wq[t * 128 + c]);
#pragma unroll
            for (int k = 0; k < 8; ++k) {
                const float4 td = *reinterpret_cast<const float4*>(&tid_s[k][c]);
                aqt[k] += wq.x * td.x + wq.y * td.y + wq.z * td.z + wq.w * td.w;
            }
        }
#pragma unroll
        for (int k = 0; k < 8; ++k) qt_o[(bb + k) * 128 + t] = aqt[k];
    }
}

// ---------------- K3: pipelined MFMA score GEMM ----------------
// Transposed MFMA (A-op = M rows, B-op = gathered rows). M fragments live in
// VGPRs (loaded once). Block owns ~13 consecutive 64-row groups; A staging is
// double-buffered: loads for group g+1 issue under compute of group g.
__global__ __launch_bounds__(256, 2) void k3_scores(
    const short* __restrict__ Mbf, const short* __restrict__ item_bf,
    const int* __restrict__ hist_g, const float* __restrict__ qu_,
    const float* __restrict__ qt_, const float* __restrict__ v_attn,
    float* __restrict__ scu, float* __restrict__ sci) {
    __shared__ __align__(16) short A_lds[2][4][4][4][16][8];  // [buf][tile][ks][hi][lo][8] = 32KB
    __shared__ float q_lds[6][2][128];                        // [bs][side][e] = 6KB
    __shared__ float v_lds[128];

    const int t = threadIdx.x;
    const int blk = blockIdx.x;
    const int gstart = (blk * GROUPS_TOTAL) / K3_BLOCKS;
    const int gend = ((blk + 1) * GROUPS_TOTAL) / K3_BLOCKS;
    const int b0 = (gstart * 64) / L_;

    // stage q rows (<=6 batches per block) + v
    for (int i = t; i < 6 * 2 * 128; i += 256) {
        const int bs = i >> 8, side = (i >> 7) & 1, e = i & 127;
        const int bc = min(b0 + bs, B_ - 1);
        q_lds[bs][side][e] = side ? qt_[bc * 128 + e] : qu_[bc * 128 + e];
    }
    if (t < 128) v_lds[t] = v_attn[t];

    const int l = t & 63, lo = l & 15, hi = l >> 4;
    const int w = t >> 6;

    // M fragments -> registers (once)
    short8v Mreg[32];
#pragma unroll
    for (int t8 = 0; t8 < 8; ++t8)
#pragma unroll
        for (int ks = 0; ks < 4; ++ks)
            Mreg[t8 * 4 + ks] = *reinterpret_cast<const short8v*>(
                Mbf + (t8 * 16 + lo) * 128 + ks * 32 + hi * 8);

    // gather staging: thread t handles row (t>>2) of the group, chunk base c0=t&3;
    // chunk k = c0 + 4*j  ->  (ks=j, hi=c0)
    const int rrow = t >> 2, c0 = t & 3;
    short8v st[4];
    {
        const int r = gstart * 64 + rrow;
        const short* rp = item_bf + (long)hist_g[r] * 128;
#pragma unroll
        for (int j = 0; j < 4; ++j)
            st[j] = *reinterpret_cast<const short8v*>(rp + (c0 + 4 * j) * 8);
    }

    for (int g = gstart; g < gend; ++g) {
        const int buf = g & 1;
        __syncthreads();  // previous compute on this buffer done
#pragma unroll
        for (int j = 0; j < 4; ++j)
            *reinterpret_cast<short8v*>(&A_lds[buf][rrow >> 4][j][c0][rrow & 15][0]) = st[j];
        __syncthreads();
        if (g + 1 < gend) {
            const int r = (g + 1) * 64 + rrow;
            const short* rp = item_bf + (long)hist_g[r] * 128;
#pragma unroll
            for (int j = 0; j < 4; ++j)
                st[j] = *reinterpret_cast<const short8v*>(rp + (c0 + 4 * j) * 8);
        }

        // compute: wave w owns tile w (rows g*64 + w*16 + lo)
        const int r = g * 64 + w * 16 + lo;
        const int bs = r / L_ - b0;
        short8v bfrag[4];
#pragma unroll
        for (int ks = 0; ks < 4; ++ks)
            bfrag[ks] = *reinterpret_cast<const short8v*>(&A_lds[buf][w][ks][hi][lo][0]);

        float su = 0.f, si = 0.f;
#pragma unroll
        for (int h2 = 0; h2 < 2; ++h2) {
            floatx4 acc[4];
#pragma unroll
            for (int q4 = 0; q4 < 4; ++q4) acc[q4] = (floatx4){0.f, 0.f, 0.f, 0.f};
#pragma unroll
            for (int ks = 0; ks < 4; ++ks)
#pragma unroll
                for (int q4 = 0; q4 < 4; ++q4)
                    acc[q4] = __builtin_amdgcn_mfma_f32_16x16x32_bf16(
                        Mreg[(h2 * 4 + q4) * 4 + ks], bfrag[ks], acc[q4], 0, 0, 0);
#pragma unroll
            for (int q4 = 0; q4 < 4; ++q4) {
                const int t8 = h2 * 4 + q4;
                const floatx4 vv = *reinterpret_cast<const floatx4*>(&v_lds[t8 * 16 + hi * 4]);
                const floatx4 qa = *reinterpret_cast<const floatx4*>(&q_lds[bs][0][t8 * 16 + hi * 4]);
                const floatx4 qb = *reinterpret_cast<const floatx4*>(&q_lds[bs][1][t8 * 16 + hi * 4]);
                float a[4], c[4];
                float mx = 0.f;
#pragma unroll
                for (int rg = 0; rg < 4; ++rg) {
                    a[rg] = qa[rg] + acc[q4][rg];
                    c[rg] = qb[rg] + acc[q4][rg];
                    mx = fmaxf(mx, fmaxf(fabsf(a[rg]), fabsf(c[rg])));
                }
                if (mx <= 0.5f) {
#pragma unroll
                    for (int rg = 0; rg < 4; ++rg) {
                        su += vv[rg] * tanh_poly(a[rg]);
                        si += vv[rg] * tanh_poly(c[rg]);
                    }
                } else {
#pragma unroll
                    for (int rg = 0; rg < 4; ++rg) {
                        su += vv[rg] * fast_tanh(a[rg]);
                        si += vv[rg] * fast_tanh(c[rg]);
                    }
                }
            }
        }
        su += __shfl_xor(su, 16, 64);
        su += __shfl_xor(su, 32, 64);
        si += __shfl_xor(si, 16, 64);
        si += __shfl_xor(si, 32, 64);
        if (hi == 0) {
            scu[r] = su * 0.25f;  // /TAU
            sci[r] = si * 0.25f;
        }
    }
}

// ---------------- K45: softmax + KL + attn apply + W_h + LN + logit ----------------
__global__ __launch_bounds__(256) void k45_fused(
    const float* __restrict__ scu, const float* __restrict__ sci,
    const float* __restrict__ maskf, const float* __restrict__ noise_u,
    const float* __restrict__ noise_i, const int* __restrict__ hist_g,
    const short* __restrict__ item_bf, const float* __restrict__ W_h,
    const float* __restrict__ uid, const float* __restrict__ tid,
    const float* __restrict__ gamma_u, const float* __restrict__ beta_u,
    const float* __restrict__ gamma_i, const float* __restrict__ beta_i,
    const float* __restrict__ pred_W, const float* __restrict__ pred_b,
    float* __restrict__ klu, float* __restrict__ kli, float* __restrict__ msm,
    float* __restrict__ out) {
    const int b = blockIdx.x, t = threadIdx.x;
    const int wid = t >> 6, lane = t & 63;
    const int base = b * L_;

    __shared__ float au[L_], ai[L_];
    __shared__ int hg[L_];
    __shared__ float aru[128], ari[128];
    __shared__ float parts[2][2][128];
    __shared__ float ui_s[2][128];
    __shared__ float red[8];

    for (int l0 = t; l0 < L_; l0 += 256) hg[l0] = hist_g[base + l0];

    // ---- Phase A (redundant per wave, barrier-free wave reductions) ----
    {
        const float* sc_[2] = {scu, sci};
        const float* nz_[2] = {noise_u, noise_i};
        float attv[2][4], kls_[2];
        float mk[4];
        float msl = 0.f;
#pragma unroll
        for (int k = 0; k < 4; ++k) {
            const int l = lane + 64 * k;
            mk[k] = (l < L_) ? maskf[base + l] : 0.f;
            msl += mk[k];
        }
        const float msum = wave_sum(msl);
#pragma unroll
        for (int side = 0; side < 2; ++side) {
            float s[4];
            float mloc = -1e30f;
#pragma unroll
            for (int k = 0; k < 4; ++k) {
                const int l = lane + 64 * k;
                s[k] = (l < L_) ? (mk[k] > 0.5f ? sc_[side][base + l] : -1e9f) : -1e30f;
                mloc = fmaxf(mloc, s[k]);
            }
            const float mx = wave_max(mloc);
            float e[4], esum = 0.f;
#pragma unroll
            for (int k = 0; k < 4; ++k) {
                const int l = lane + 64 * k;
                e[k] = (l < L_) ? expf(s[k] - mx) : 0.f;
                esum += e[k];
            }
            const float Z = wave_sum(esum);
            const float invZ = 1.f / Z;
            float wt[4], wsum = 0.f, klsum = 0.f;
#pragma unroll
            for (int k = 0; k < 4; ++k) {
                const int l = lane + 64 * k;
                const float phi = e[k] * invZ;
                const float mu = logf(phi + 1e-8f);
                wt[k] = (l < L_) ? expf(mu + 0.1f * nz_[side][base + l]) * mk[k] : 0.f;
                wsum += wt[k];
                klsum += (l < L_) ? (2.3025850929940457f + 0.5f * (0.01f + mu * mu) - 0.5f) * mk[k] : 0.f;
            }
            const float Zw = wave_sum(wsum);
            const float invZw = 1.f / (Zw + 1e-8f);
#pragma unroll
            for (int k = 0; k < 4; ++k) attv[side][k] = wt[k] * invZw;
            kls_[side] = wave_sum(klsum);
        }
        if (wid == 0) {
#pragma unroll
            for (int k = 0; k < 4; ++k) {
                const int l = lane + 64 * k;
                if (l < L_) au[l] = attv[0][k];
            }
        } else if (wid == 1) {
#pragma unroll
            for (int k = 0; k < 4; ++k) {
                const int l = lane + 64 * k;
                if (l < L_) ai[l] = attv[1][k];
            }
        } else if (wid == 2 && lane == 0) {
            klu[b] = kls_[0];
            kli[b] = kls_[1];
            msm[b] = msum;
        }
    }
    __syncthreads();

    // ---- Phase B: attn-weighted gather-sum, l-range split in halves ----
    const int half = t >> 7, tl = t & 127;
    {
        float su = 0.f, si = 0.f;
        const int l0 = half * 100;
#pragma unroll 4
        for (int l = l0; l < l0 + 100; ++l) {
            const float h = bf2f(item_bf[(long)hg[l] * 128 + tl]);
            su += au[l] * h;
            si += ai[l] * h;
        }
        parts[0][half][tl] = su;
        parts[1][half][tl] = si;
    }
    __syncthreads();
    if (half == 0) aru[tl] = parts[0][0][tl] + parts[0][1][tl];
    else           ari[tl] = parts[1][0][tl] + parts[1][1][tl];
    __syncthreads();

    // ---- Phase C: W_h matvec (half 0 = u, half 1 = i), LN, logit ----
    const float* vsrc = half ? ari : aru;
    float o = 0.f;
#pragma unroll 2
    for (int c = 0; c < 128; c += 4) {
        const float4 w = *reinterpret_cast<const float4*>(&W_h[tl * 128 + c]);
        o += w.x * vsrc[c] + w.y * vsrc[c + 1] + w.z * vsrc[c + 2] + w.w * vsrc[c + 3];
    }
    const float x = o * (half ? tid[b * 128 + tl] : uid[b * 128 + tl]);

    float v1 = wave_sum(x);
    if (lane == 0) red[wid] = v1;
    __syncthreads();
    const float mean = (red[half * 2] + red[half * 2 + 1]) * (1.f / 128.f);
    const float d = x - mean;
    float v2 = wave_sum(d * d);
    __syncthreads();
    if (lane == 0) red[wid] = v2;
    __syncthreads();
    const float var = (red[half * 2] + red[half * 2 + 1]) * (1.f / 128.f);
    const float gmm = half ? gamma_i[tl] : gamma_u[tl];
    const float bta = half ? beta_i[tl] : beta_u[tl];
    ui_s[half][tl] = d * rsqrtf(var + 1e-5f) * gmm + bta;
    __syncthreads();
    if (half == 0) {
        const float p = ui_s[0][tl] * ui_s[1][tl] * pred_W[tl];
        const float v3 = wave_sum(p);
        if (lane == 0) red[4 + wid] = v3;
    }
    __syncthreads();
    if (t == 0) out[b] = red[4] + red[5] + pred_b[0];
}

// ---------------- K6: KL final reduction ----------------
__global__ __launch_bounds__(256) void k6_kl(const float* __restrict__ klu,
                                             const float* __restrict__ kli,
                                             const float* __restrict__ msm,
                                             float* __restrict__ out) {
    __shared__ float red[4];
    const int t = threadIdx.x;
    float su = 0.f, si = 0.f, sm = 0.f;
    for (int b = t; b < B_; b += 256) {
        su += klu[b];
        si += kli[b];
        sm += msm[b];
    }
    su = wave_sum(su);
    si = wave_sum(si);
    sm = wave_sum(sm);
    __syncthreads();
    if ((t & 63) == 0) red[t >> 6] = su;
    __syncthreads();
    su = red[0] + red[1] + red[2] + red[3];
    __syncthreads();
    if ((t & 63) == 0) red[t >> 6] = si;
    __syncthreads();
    si = red[0] + red[1] + red[2] + red[3];
    __syncthreads();
    if ((t & 63) == 0) red[t >> 6] = sm;
    __syncthreads();
    sm = red[0] + red[1] + red[2] + red[3];
    if (t == 0) {
        const float inv = 1.f / (sm + 1e-8f);
        out[0] = 0.5f * (su * inv + si * inv);
    }
}

extern "C" void kernel_launch(void* const* d_in, const int* in_sizes, int n_in,
                              void* d_out, int out_size, void* d_ws, size_t ws_size,
                              hipStream_t stream) {
    const int* user_idx = (const int*)d_in[0];
    const int* item_idx = (const int*)d_in[1];
    const int* user_hist = (const int*)d_in[2];
    const float* user_embed = (const float*)d_in[3];
    const float* item_embed = (const float*)d_in[4];
    const float* W_i = (const float*)d_in[5];
    const float* W_h = (const float*)d_in[6];
    const float* Wq = (const float*)d_in[7];
    const float* Wk = (const float*)d_in[8];
    const float* v_attn = (const float*)d_in[9];
    const float* pred_W = (const float*)d_in[10];
    const float* pred_b = (const float*)d_in[11];
    const float* gamma_u = (const float*)d_in[12];
    const float* beta_u = (const float*)d_in[13];
    const float* gamma_i = (const float*)d_in[14];
    const float* beta_i = (const float*)d_in[15];
    const float* noise_u = (const float*)d_in[16];
    const float* noise_i = (const float*)d_in[17];
    float* out = (float*)d_out;

    char* ws = (char*)d_ws;
    size_t off = 0;
    auto alloc = [&](size_t bytes) -> void* {
        void* p = ws + off;
        off = (off + bytes + 255) & ~(size_t)255;
        return p;
    };
    short* Mbf     = (short*)alloc(128 * 128 * 2);
    short* item_bf = (short*)alloc((size_t)(NITEMS + 1) * 128 * 2);
    float* uid = (float*)alloc((size_t)B_ * 128 * 4);
    float* tid = (float*)alloc((size_t)B_ * 128 * 4);
    float* qu  = (float*)alloc((size_t)B_ * 128 * 4);
    float* qt  = (float*)alloc((size_t)B_ * 128 * 4);
    int* hg    = (int*)alloc((size_t)B_ * L_ * 4);
    float* mkf = (float*)alloc((size_t)B_ * L_ * 4);
    float* scu = (float*)alloc((size_t)B_ * L_ * 4);
    float* sci = (float*)alloc((size_t)B_ * L_ * 4);
    float* klu = (float*)alloc((size_t)B_ * 4);
    float* kli = (float*)alloc((size_t)B_ * 4);
    float* msm = (float*)alloc((size_t)B_ * 4);

    const int n8 = (NITEMS + 1) * 128 / 8;
    k0_cvt<<<(n8 + 255) / 256, 256, 0, stream>>>(item_embed, item_bf, n8);
    k1_M<<<128, 128, 0, stream>>>(Wk, W_h, Mbf);
    k2_prep<<<B_ / 8, 128, 0, stream>>>(user_idx, item_idx, user_hist, user_embed,
                                        item_embed, W_i, Wq, uid, tid, qu, qt, hg, mkf);
    k3_scores<<<K3_BLOCKS, 256, 0, stream>>>(Mbf, item_bf, hg, qu, qt, v_attn, scu, sci);
    k45_fused<<<B_, 256, 0, stream>>>(scu, sci, mkf, noise_u, noise_i, hg, item_bf,
                                      W_h, uid, tid, gamma_u, beta_u, gamma_i, beta_i,
                                      pred_W, pred_b, klu, kli, msm, out);
    k6_kl<<<1, 256, 0, stream>>>(klu, kli, msm, out + B_);
}

// Round 7
// 138.836 us; speedup vs baseline: 1.9452x; 1.0488x over previous
//
#include <hip/hip_runtime.h>

#define B_ 2048
#define L_ 200
#define D_ 128
#define NITEMS 50000
#define NROWS (B_ * L_)            // 409600
#define NTILES (NROWS / 16)        // 25600
#define K3_BLOCKS 512
#define TPB (NTILES / K3_BLOCKS)   // 50 tiles (800 rows = 4 batches) per block

typedef __attribute__((ext_vector_type(8))) short short8v;
typedef __attribute__((ext_vector_type(4))) float floatx4;

// ---------------- helpers ----------------
__device__ __forceinline__ short f2bf(float f) {
    union { float f; unsigned u; } v;
    v.f = f;
    unsigned r = v.u + 0x7FFFu + ((v.u >> 16) & 1u);
    return (short)(r >> 16);
}
__device__ __forceinline__ float bf2f(short s) {
    union { unsigned u; float f; } v;
    v.u = ((unsigned)(unsigned short)s) << 16;
    return v.f;
}

__device__ __forceinline__ float fast_tanh(float x) {
    x = fminf(fmaxf(x, -15.f), 15.f);
    const float t = exp2f(x * 2.885390081777927f);  // e^(2x)
    return (t - 1.f) * __builtin_amdgcn_rcpf(t + 1.f);
}
// Taylor to x^7, |x|<=0.5: err < 5e-5
__device__ __forceinline__ float tanh_poly(float x) {
    const float x2 = x * x;
    return x + x * x2 * (-0.33333333f + x2 * (0.13333333f + x2 * (-0.05396825f)));
}

__device__ __forceinline__ float wave_sum(float v) {
#pragma unroll
    for (int m = 32; m >= 1; m >>= 1) v += __shfl_xor(v, m, 64);
    return v;
}
__device__ __forceinline__ float wave_max(float v) {
#pragma unroll
    for (int m = 32; m >= 1; m >>= 1) v = fmaxf(v, __shfl_xor(v, m, 64));
    return v;
}

// async global->LDS, 16B per lane, HW dest = lds_base + lane*16
__device__ __forceinline__ void gload_lds16(const short* g, short* l) {
    __builtin_amdgcn_global_load_lds(
        (const __attribute__((address_space(1))) void*)g,
        (__attribute__((address_space(3))) void*)l, 16, 0, 0);
}

// ---------------- K0: item_embed -> bf16 table ----------------
__global__ __launch_bounds__(256) void k0_cvt(const float* __restrict__ src,
                                              short* __restrict__ dst, int n8) {
    const int i = blockIdx.x * 256 + threadIdx.x;
    if (i >= n8) return;
    const float4 f0 = *reinterpret_cast<const float4*>(src + i * 8);
    const float4 f1 = *reinterpret_cast<const float4*>(src + i * 8 + 4);
    short8v w;
    w[0] = f2bf(f0.x); w[1] = f2bf(f0.y); w[2] = f2bf(f0.z); w[3] = f2bf(f0.w);
    w[4] = f2bf(f1.x); w[5] = f2bf(f1.y); w[6] = f2bf(f1.z); w[7] = f2bf(f1.w);
    *reinterpret_cast<short8v*>(dst + i * 8) = w;
}

// ---------------- K1: Mbf = bf16( Wk @ W_h ) ----------------
__global__ __launch_bounds__(128) void k1_M(const float* __restrict__ Wk,
                                            const float* __restrict__ Wh,
                                            short* __restrict__ Mbf) {
    __shared__ float wk[128];
    const int e = blockIdx.x, c = threadIdx.x;
    wk[c] = Wk[e * 128 + c];
    __syncthreads();
    float s = 0.f;
#pragma unroll 4
    for (int d = 0; d < 128; ++d) s += wk[d] * Wh[d * 128 + c];
    Mbf[e * 128 + c] = f2bf(s);
}

// ---------------- K2: batched per-b prep (8 b per block) ----------------
__global__ __launch_bounds__(128) void k2_prep(
    const int* __restrict__ user_idx, const int* __restrict__ item_idx,
    const int* __restrict__ user_hist, const float* __restrict__ user_embed,
    const float* __restrict__ item_embed, const float* __restrict__ W_i,
    const float* __restrict__ Wq, float* __restrict__ uid_o,
    float* __restrict__ tid_o, float* __restrict__ qu_o, float* __restrict__ qt_o,
    int* __restrict__ hist_o, float* __restrict__ maskf_o) {
    const int bb = blockIdx.x * 8, t = threadIdx.x;
    __shared__ float uid_s[8][128], traw_s[8][128], tid_s[8][128];
    __shared__ int ui_s[8], ii_s[8];
    if (t < 8) {
        ui_s[t] = user_idx[bb + t];
        ii_s[t] = item_idx[bb + t];
    }
    __syncthreads();
#pragma unroll
    for (int k = 0; k < 8; ++k) {
        const float uv = user_embed[(long)ui_s[k] * 128 + t];
        const float tv = item_embed[(long)ii_s[k] * 128 + t];
        uid_s[k][t] = uv;
        traw_s[k][t] = tv;
        uid_o[(bb + k) * 128 + t] = uv;
        for (int l = t; l < L_; l += 128) {
            const int hv = user_hist[(long)ui_s[k] * L_ + l];
            hist_o[(bb + k) * L_ + l] = hv;
            maskf_o[(bb + k) * L_ + l] = (hv != ii_s[k] && hv != NITEMS) ? 1.f : 0.f;
        }
    }
    __syncthreads();
    {
        float at[8] = {0.f, 0.f, 0.f, 0.f, 0.f, 0.f, 0.f, 0.f};
        float aq[8] = {0.f, 0.f, 0.f, 0.f, 0.f, 0.f, 0.f, 0.f};
        for (int c = 0; c < 128; c += 4) {
            const float4 wi = *reinterpret_cast<const float4*>(&W_i[t * 128 + c]);
            const float4 wq = *reinterpret_cast<const float4*>(&Wq[t * 128 + c]);
#pragma unroll
            for (int k = 0; k < 8; ++k) {
                const float4 tr = *reinterpret_cast<const float4*>(&traw_s[k][c]);
                const float4 ud = *reinterpret_cast<const float4*>(&uid_s[k][c]);
                at[k] += wi.x * tr.x + wi.y * tr.y + wi.z * tr.z + wi.w * tr.w;
                aq[k] += wq.x * ud.x + wq.y * ud.y + wq.z * ud.z + wq.w * ud.w;
            }
        }
#pragma unroll
        for (int k = 0; k < 8; ++k) {
            tid_s[k][t] = at[k];
            tid_o[(bb + k) * 128 + t] = at[k];
            qu_o[(bb + k) * 128 + t] = aq[k];
        }
    }
    __syncthreads();
    {
        float aqt[8] = {0.f, 0.f, 0.f, 0.f, 0.f, 0.f, 0.f, 0.f};
        for (int c = 0; c < 128; c += 4) {
            const float4 wq = *reinterpret_cast<const float4*>(&Wq[t * 128 + c]);
#pragma unroll
            for (int k = 0; k < 8; ++k) {
                const float4 td = *reinterpret_cast<const float4*>(&tid_s[k][c]);
                aqt[k] += wq.x * td.x + wq.y * td.y + wq.z * td.z + wq.w * td.w;
            }
        }
#pragma unroll
        for (int k = 0; k < 8; ++k) qt_o[(bb + k) * 128 + t] = aqt[k];
    }
}

// ---------------- K3: barrier-free pipelined MFMA score GEMM ----------------
// Per-wave private double-buffered A tiles staged via global_load_lds;
// counted vmcnt (never 0 in steady state) keeps next tile's gather in flight
// under current tile's MFMA+tanh. No __syncthreads after init.
__global__ __launch_bounds__(256, 2) void k3_scores(
    const short* __restrict__ Mbf, const short* __restrict__ item_bf,
    const int* __restrict__ hist_g, const float* __restrict__ qu_,
    const float* __restrict__ qt_, const float* __restrict__ v_attn,
    float* __restrict__ scu, float* __restrict__ sci) {
    __shared__ __align__(16) short A_lds[4][2][4][4][16][8];  // [wave][buf][ks][hi][lo][8] = 32KB
    __shared__ float q_lds[4][2][128];                        // [bs][side][e] = 4KB
    __shared__ float v_lds[128];

    const int t = threadIdx.x, blk = blockIdx.x;
    const int b0 = blk * 4;

    for (int i = t; i < 4 * 2 * 128; i += 256) {
        const int bs = i >> 8, side = (i >> 7) & 1, e = i & 127;
        q_lds[bs][side][e] = side ? qt_[(b0 + bs) * 128 + e] : qu_[(b0 + bs) * 128 + e];
    }
    if (t < 128) v_lds[t] = v_attn[t];
    __syncthreads();  // the only block barrier

    const int w = t >> 6, l = t & 63, lo = l & 15, hi = l >> 4;

    // M fragments -> registers (once)
    short8v Mreg[32];
#pragma unroll
    for (int t8 = 0; t8 < 8; ++t8)
#pragma unroll
        for (int ks = 0; ks < 4; ++ks)
            Mreg[t8 * 4 + ks] = *reinterpret_cast<const short8v*>(
                Mbf + (t8 * 16 + lo) * 128 + ks * 32 + hi * 8);

    const int tstart = blk * TPB + (w * TPB) / 4;
    const int tend = blk * TPB + ((w + 1) * TPB) / 4;
    const int n = tend - tstart;

    short* abase = &A_lds[w][0][0][0][0][0];
    const int koff = hi * 8;  // chunk offset within a ks-segment (per lane)

    // prologue: hist offset + stage tile tstart into buf 0
    int tcur = tstart;
    long roff;
    {
        roff = (long)hist_g[tcur * 16 + lo] * 128;
        const short* rp = item_bf + roff + koff;
#pragma unroll
        for (int ks = 0; ks < 4; ++ks)
            gload_lds16(rp + ks * 32, abase + ks * 512);
    }
    long roff_n = (long)hist_g[min((tcur + 1) * 16 + lo, NROWS - 1)] * 128;

    int buf = 0;
    for (int i = 0; i < n; ++i, ++tcur, buf ^= 1) {
        if (i + 1 < n) {
            // hist prefetch for t+2 issues first (older than next gloads)
            const long rtmp = roff_n;
            const long roff_f = (long)hist_g[min((tcur + 2) * 16 + lo, NROWS - 1)] * 128;
            const short* rp = item_bf + rtmp + koff;
            short* dst = abase + (buf ^ 1) * 2048;
#pragma unroll
            for (int ks = 0; ks < 4; ++ks)
                gload_lds16(rp + ks * 32, dst + ks * 512);
            roff_n = roff_f;
            asm volatile("s_waitcnt vmcnt(5)" ::: "memory");
        } else {
            asm volatile("s_waitcnt vmcnt(0)" ::: "memory");
        }
        __builtin_amdgcn_sched_barrier(0);

        // ---- compute tile tcur from buf ----
        const short* src = abase + buf * 2048;
        short8v bfrag[4];
#pragma unroll
        for (int ks = 0; ks < 4; ++ks)
            bfrag[ks] = *reinterpret_cast<const short8v*>(src + ks * 512 + hi * 128 + lo * 8);

        const int r = tcur * 16 + lo;
        const int lr = r - blk * 800;
        const int bs = (lr >= 200) + (lr >= 400) + (lr >= 600);

        float su = 0.f, si = 0.f;
#pragma unroll
        for (int h2 = 0; h2 < 2; ++h2) {
            floatx4 acc[4];
#pragma unroll
            for (int q4 = 0; q4 < 4; ++q4) acc[q4] = (floatx4){0.f, 0.f, 0.f, 0.f};
#pragma unroll
            for (int ks = 0; ks < 4; ++ks)
#pragma unroll
                for (int q4 = 0; q4 < 4; ++q4)
                    acc[q4] = __builtin_amdgcn_mfma_f32_16x16x32_bf16(
                        Mreg[(h2 * 4 + q4) * 4 + ks], bfrag[ks], acc[q4], 0, 0, 0);
#pragma unroll
            for (int q4 = 0; q4 < 4; ++q4) {
                const int t8 = h2 * 4 + q4;
                const floatx4 vv = *reinterpret_cast<const floatx4*>(&v_lds[t8 * 16 + hi * 4]);
                const floatx4 qa = *reinterpret_cast<const floatx4*>(&q_lds[bs][0][t8 * 16 + hi * 4]);
                const floatx4 qb = *reinterpret_cast<const floatx4*>(&q_lds[bs][1][t8 * 16 + hi * 4]);
                float a[4], c[4];
                float mx = 0.f;
#pragma unroll
                for (int rg = 0; rg < 4; ++rg) {
                    a[rg] = qa[rg] + acc[q4][rg];
                    c[rg] = qb[rg] + acc[q4][rg];
                    mx = fmaxf(mx, fmaxf(fabsf(a[rg]), fabsf(c[rg])));
                }
                if (mx <= 0.5f) {
#pragma unroll
                    for (int rg = 0; rg < 4; ++rg) {
                        su += vv[rg] * tanh_poly(a[rg]);
                        si += vv[rg] * tanh_poly(c[rg]);
                    }
                } else {
#pragma unroll
                    for (int rg = 0; rg < 4; ++rg) {
                        su += vv[rg] * fast_tanh(a[rg]);
                        si += vv[rg] * fast_tanh(c[rg]);
                    }
                }
            }
        }
        su += __shfl_xor(su, 16, 64);
        su += __shfl_xor(su, 32, 64);
        si += __shfl_xor(si, 16, 64);
        si += __shfl_xor(si, 32, 64);
        if (hi == 0) {
            scu[r] = su * 0.25f;  // /TAU
            sci[r] = si * 0.25f;
        }
    }
}

// ---------------- K45: softmax + KL + attn apply + W_h + LN + logit ----------------
__global__ __launch_bounds__(256) void k45_fused(
    const float* __restrict__ scu, const float* __restrict__ sci,
    const float* __restrict__ maskf, const float* __restrict__ noise_u,
    const float* __restrict__ noise_i, const int* __restrict__ hist_g,
    const short* __restrict__ item_bf, const float* __restrict__ W_h,
    const float* __restrict__ uid, const float* __restrict__ tid,
    const float* __restrict__ gamma_u, const float* __restrict__ beta_u,
    const float* __restrict__ gamma_i, const float* __restrict__ beta_i,
    const float* __restrict__ pred_W, const float* __restrict__ pred_b,
    float* __restrict__ klu, float* __restrict__ kli, float* __restrict__ msm,
    float* __restrict__ out) {
    const int b = blockIdx.x, t = threadIdx.x;
    const int wid = t >> 6, lane = t & 63;
    const int base = b * L_;

    __shared__ float au[L_], ai[L_];
    __shared__ int hg[L_];
    __shared__ float aru[128], ari[128];
    __shared__ float parts[2][4][128];
    __shared__ float ui_s[2][128];
    __shared__ float red[8];

    for (int l0 = t; l0 < L_; l0 += 256) hg[l0] = hist_g[base + l0];

    // ---- Phase A (redundant per wave, barrier-free wave reductions) ----
    {
        const float* sc_[2] = {scu, sci};
        const float* nz_[2] = {noise_u, noise_i};
        float attv[2][4], kls_[2];
        float mk[4];
        float msl = 0.f;
#pragma unroll
        for (int k = 0; k < 4; ++k) {
            const int l = lane + 64 * k;
            mk[k] = (l < L_) ? maskf[base + l] : 0.f;
            msl += mk[k];
        }
        const float msum = wave_sum(msl);
#pragma unroll
        for (int side = 0; side < 2; ++side) {
            float s[4];
            float mloc = -1e30f;
#pragma unroll
            for (int k = 0; k < 4; ++k) {
                const int l = lane + 64 * k;
                s[k] = (l < L_) ? (mk[k] > 0.5f ? sc_[side][base + l] : -1e9f) : -1e30f;
                mloc = fmaxf(mloc, s[k]);
            }
            const float mx = wave_max(mloc);
            float e[4], esum = 0.f;
#pragma unroll
            for (int k = 0; k < 4; ++k) {
                const int l = lane + 64 * k;
                e[k] = (l < L_) ? expf(s[k] - mx) : 0.f;
                esum += e[k];
            }
            const float Z = wave_sum(esum);
            const float invZ = 1.f / Z;
            float wt[4], wsum = 0.f, klsum = 0.f;
#pragma unroll
            for (int k = 0; k < 4; ++k) {
                const int l = lane + 64 * k;
                const float phi = e[k] * invZ;
                const float mu = logf(phi + 1e-8f);
                wt[k] = (l < L_) ? expf(mu + 0.1f * nz_[side][base + l]) * mk[k] : 0.f;
                wsum += wt[k];
                klsum += (l < L_) ? (2.3025850929940457f + 0.5f * (0.01f + mu * mu) - 0.5f) * mk[k] : 0.f;
            }
            const float Zw = wave_sum(wsum);
            const float invZw = 1.f / (Zw + 1e-8f);
#pragma unroll
            for (int k = 0; k < 4; ++k) attv[side][k] = wt[k] * invZw;
            kls_[side] = wave_sum(klsum);
        }
        if (wid == 0) {
#pragma unroll
            for (int k = 0; k < 4; ++k) {
                const int l = lane + 64 * k;
                if (l < L_) au[l] = attv[0][k];
            }
        } else if (wid == 1) {
#pragma unroll
            for (int k = 0; k < 4; ++k) {
                const int l = lane + 64 * k;
                if (l < L_) ai[l] = attv[1][k];
            }
        } else if (wid == 2 && lane == 0) {
            klu[b] = kls_[0];
            kli[b] = kls_[1];
            msm[b] = msum;
        }
    }
    __syncthreads();

    // ---- Phase B: attn-weighted gather-sum; 4 row-groups x 64 lanes (dword loads) ----
    {
        const int rg = t >> 6, c2 = t & 63;
        float s00 = 0.f, s01 = 0.f, s10 = 0.f, s11 = 0.f;
        const int lbeg = rg * 50;
        for (int l = lbeg; l < lbeg + 50; ++l) {
            const unsigned hv =
                *reinterpret_cast<const unsigned*>(item_bf + (long)hg[l] * 128 + c2 * 2);
            const float h0 = bf2f((short)(hv & 0xffffu));
            const float h1 = bf2f((short)(hv >> 16));
            const float a0 = au[l], a1 = ai[l];
            s00 += a0 * h0; s01 += a0 * h1;
            s10 += a1 * h0; s11 += a1 * h1;
        }
        parts[0][rg][c2 * 2] = s00;
        parts[0][rg][c2 * 2 + 1] = s01;
        parts[1][rg][c2 * 2] = s10;
        parts[1][rg][c2 * 2 + 1] = s11;
    }
    __syncthreads();
    const int half = t >> 7, tl = t & 127;
    if (half == 0)
        aru[tl] = parts[0][0][tl] + parts[0][1][tl] + parts[0][2][tl] + parts[0][3][tl];
    else
        ari[tl] = parts[1][0][tl] + parts[1][1][tl] + parts[1][2][tl] + parts[1][3][tl];
    __syncthreads();

    // ---- Phase C: W_h matvec (half 0 = u, half 1 = i), LN, logit ----
    const float* vsrc = half ? ari : aru;
    float o = 0.f;
#pragma unroll 2
    for (int c = 0; c < 128; c += 4) {
        const float4 w = *reinterpret_cast<const float4*>(&W_h[tl * 128 + c]);
        o += w.x * vsrc[c] + w.y * vsrc[c + 1] + w.z * vsrc[c + 2] + w.w * vsrc[c + 3];
    }
    const float x = o * (half ? tid[b * 128 + tl] : uid[b * 128 + tl]);

    float v1 = wave_sum(x);
    if (lane == 0) red[wid] = v1;
    __syncthreads();
    const float mean = (red[half * 2] + red[half * 2 + 1]) * (1.f / 128.f);
    const float d = x - mean;
    float v2 = wave_sum(d * d);
    __syncthreads();
    if (lane == 0) red[wid] = v2;
    __syncthreads();
    const float var = (red[half * 2] + red[half * 2 + 1]) * (1.f / 128.f);
    const float gmm = half ? gamma_i[tl] : gamma_u[tl];
    const float bta = half ? beta_i[tl] : beta_u[tl];
    ui_s[half][tl] = d * rsqrtf(var + 1e-5f) * gmm + bta;
    __syncthreads();
    if (half == 0) {
        const float p = ui_s[0][tl] * ui_s[1][tl] * pred_W[tl];
        const float v3 = wave_sum(p);
        if (lane == 0) red[4 + wid] = v3;
    }
    __syncthreads();
    if (t == 0) out[b] = red[4] + red[5] + pred_b[0];
}

// ---------------- K6: KL final reduction ----------------
__global__ __launch_bounds__(256) void k6_kl(const float* __restrict__ klu,
                                             const float* __restrict__ kli,
                                             const float* __restrict__ msm,
                                             float* __restrict__ out) {
    __shared__ float red[4];
    const int t = threadIdx.x;
    float su = 0.f, si = 0.f, sm = 0.f;
    for (int b = t; b < B_; b += 256) {
        su += klu[b];
        si += kli[b];
        sm += msm[b];
    }
    su = wave_sum(su);
    si = wave_sum(si);
    sm = wave_sum(sm);
    __syncthreads();
    if ((t & 63) == 0) red[t >> 6] = su;
    __syncthreads();
    su = red[0] + red[1] + red[2] + red[3];
    __syncthreads();
    if ((t & 63) == 0) red[t >> 6] = si;
    __syncthreads();
    si = red[0] + red[1] + red[2] + red[3];
    __syncthreads();
    if ((t & 63) == 0) red[t >> 6] = sm;
    __syncthreads();
    sm = red[0] + red[1] + red[2] + red[3];
    if (t == 0) {
        const float inv = 1.f / (sm + 1e-8f);
        out[0] = 0.5f * (su * inv + si * inv);
    }
}

extern "C" void kernel_launch(void* const* d_in, const int* in_sizes, int n_in,
                              void* d_out, int out_size, void* d_ws, size_t ws_size,
                              hipStream_t stream) {
    const int* user_idx = (const int*)d_in[0];
    const int* item_idx = (const int*)d_in[1];
    const int* user_hist = (const int*)d_in[2];
    const float* user_embed = (const float*)d_in[3];
    const float* item_embed = (const float*)d_in[4];
    const float* W_i = (const float*)d_in[5];
    const float* W_h = (const float*)d_in[6];
    const float* Wq = (const float*)d_in[7];
    const float* Wk = (const float*)d_in[8];
    const float* v_attn = (const float*)d_in[9];
    const float* pred_W = (const float*)d_in[10];
    const float* pred_b = (const float*)d_in[11];
    const float* gamma_u = (const float*)d_in[12];
    const float* beta_u = (const float*)d_in[13];
    const float* gamma_i = (const float*)d_in[14];
    const float* beta_i = (const float*)d_in[15];
    const float* noise_u = (const float*)d_in[16];
    const float* noise_i = (const float*)d_in[17];
    float* out = (float*)d_out;

    char* ws = (char*)d_ws;
    size_t off = 0;
    auto alloc = [&](size_t bytes) -> void* {
        void* p = ws + off;
        off = (off + bytes + 255) & ~(size_t)255;
        return p;
    };
    short* Mbf     = (short*)alloc(128 * 128 * 2);
    short* item_bf = (short*)alloc((size_t)(NITEMS + 1) * 128 * 2);
    float* uid = (float*)alloc((size_t)B_ * 128 * 4);
    float* tid = (float*)alloc((size_t)B_ * 128 * 4);
    float* qu  = (float*)alloc((size_t)B_ * 128 * 4);
    float* qt  = (float*)alloc((size_t)B_ * 128 * 4);
    int* hg    = (int*)alloc((size_t)B_ * L_ * 4);
    float* mkf = (float*)alloc((size_t)B_ * L_ * 4);
    float* scu = (float*)alloc((size_t)B_ * L_ * 4);
    float* sci = (float*)alloc((size_t)B_ * L_ * 4);
    float* klu = (float*)alloc((size_t)B_ * 4);
    float* kli = (float*)alloc((size_t)B_ * 4);
    float* msm = (float*)alloc((size_t)B_ * 4);

    const int n8 = (NITEMS + 1) * 128 / 8;
    k0_cvt<<<(n8 + 255) / 256, 256, 0, stream>>>(item_embed, item_bf, n8);
    k1_M<<<128, 128, 0, stream>>>(Wk, W_h, Mbf);
    k2_prep<<<B_ / 8, 128, 0, stream>>>(user_idx, item_idx, user_hist, user_embed,
                                        item_embed, W_i, Wq, uid, tid, qu, qt, hg, mkf);
    k3_scores<<<K3_BLOCKS, 256, 0, stream>>>(Mbf, item_bf, hg, qu, qt, v_attn, scu, sci);
    k45_fused<<<B_, 256, 0, stream>>>(scu, sci, mkf, noise_u, noise_i, hg, item_bf,
                                      W_h, uid, tid, gamma_u, beta_u, gamma_i, beta_i,
                                      pred_W, pred_b, klu, kli, msm, out);
    k6_kl<<<1, 256, 0, stream>>>(klu, kli, msm, out + B_);
}